// Round 1
// baseline (1150.287 us; speedup 1.0000x reference)
//
#include <hip/hip_runtime.h>
#include <hip/hip_bf16.h>

// ChildSumTreeLSTM, N=512 nodes, K=4 children, IN_DIM=MEM=1024, R=48 (+identity slot 48)
// Tree is a reversed 4-ary heap => contiguous level ranges, processed level-parallel:
//   leaves [0,384); internal phases [384,427),[427,491),[491,507),[507,511),[511,512)

#define KC 4
#define NREL 48

__device__ __forceinline__ float sigf(float x) { return 1.0f / (1.0f + __expf(-x)); }

// ---------------------------------------------------------------------------
// Generic tiled GEMM: C[m,j] = sum_k A[m,k]*W[j,k] + bias[j] (+ add[m,j] if add)
// A: M x 1024 row-major. W: NC x 1024 row-major. 256 thr, BM=BN=64, BK=16, 4x4 micro.
// LDS staged k-major so inner loop uses ds_read_b128.
// ---------------------------------------------------------------------------
__global__ __launch_bounds__(256)
void gemm_xw(const float* __restrict__ A, const float* __restrict__ W,
             const float* __restrict__ bias, const float* __restrict__ add,
             float* __restrict__ C, int M, int NC)
{
    __shared__ float As[16][64];
    __shared__ float Ws[16][64];
    const int bm = blockIdx.y * 64;
    const int bn = blockIdx.x * 64;
    const int tid = threadIdx.x;
    const int lr = tid >> 2;         // 0..63 tile row for loads
    const int lk = (tid & 3) << 2;   // 0,4,8,12
    const int ti = tid >> 4;         // 0..15
    const int tj = tid & 15;         // 0..15
    float acc[4][4] = {};
    for (int k0 = 0; k0 < 1024; k0 += 16) {
        float4 av = make_float4(0.f, 0.f, 0.f, 0.f);
        int am = bm + lr;
        if (am < M) av = *reinterpret_cast<const float4*>(A + (size_t)am * 1024 + k0 + lk);
        As[lk + 0][lr] = av.x; As[lk + 1][lr] = av.y; As[lk + 2][lr] = av.z; As[lk + 3][lr] = av.w;
        float4 wv = *reinterpret_cast<const float4*>(W + (size_t)(bn + lr) * 1024 + k0 + lk);
        Ws[lk + 0][lr] = wv.x; Ws[lk + 1][lr] = wv.y; Ws[lk + 2][lr] = wv.z; Ws[lk + 3][lr] = wv.w;
        __syncthreads();
#pragma unroll
        for (int kk = 0; kk < 16; ++kk) {
            float4 a = *reinterpret_cast<const float4*>(&As[kk][ti << 2]);
            float4 b = *reinterpret_cast<const float4*>(&Ws[kk][tj << 2]);
            float ar[4] = {a.x, a.y, a.z, a.w};
            float br[4] = {b.x, b.y, b.z, b.w};
#pragma unroll
            for (int ii = 0; ii < 4; ++ii)
#pragma unroll
                for (int jj = 0; jj < 4; ++jj)
                    acc[ii][jj] = fmaf(ar[ii], br[jj], acc[ii][jj]);
        }
        __syncthreads();
    }
#pragma unroll
    for (int ii = 0; ii < 4; ++ii) {
        int m = bm + (ti << 2) + ii;
        if (m >= M) continue;
#pragma unroll
        for (int jj = 0; jj < 4; ++jj) {
            int j = bn + (tj << 2) + jj;
            float v = acc[ii][jj] + bias[j];
            if (add) v += add[(size_t)m * NC + j];
            C[(size_t)m * NC + j] = v;
        }
    }
}

// ---------------------------------------------------------------------------
// f-gate GEMM with row gather: rows r in [0,4M), cid = child_idx[(ph0+r/4)*4 + r%4]
// fcp[r,j] = sigmoid( sum_k h[cid,k]*fh_w[j,k] + fh_b[j] + xf[ph0+r/4, j] ) * c_all[cid,j]
// (0 for padded children)
// ---------------------------------------------------------------------------
__global__ __launch_bounds__(256)
void gemm_fgate(const float* __restrict__ h, const float* __restrict__ c_all,
                const float* __restrict__ fh_w, const float* __restrict__ fh_b,
                const float* __restrict__ xf, const int* __restrict__ child_idx,
                float* __restrict__ fcp, int ph0, int M)
{
    __shared__ float As[16][64];
    __shared__ float Ws[16][64];
    const int R = 4 * M;
    const int bm = blockIdx.y * 64;
    const int bn = blockIdx.x * 64;
    const int tid = threadIdx.x;
    const int lr = tid >> 2;
    const int lk = (tid & 3) << 2;
    const int ti = tid >> 4;
    const int tj = tid & 15;
    float acc[4][4] = {};
    for (int k0 = 0; k0 < 1024; k0 += 16) {
        int r = bm + lr;
        float4 av = make_float4(0.f, 0.f, 0.f, 0.f);
        if (r < R) {
            int cid = child_idx[(ph0 + (r >> 2)) * KC + (r & 3)];
            if (cid >= 0)
                av = *reinterpret_cast<const float4*>(h + (size_t)cid * 1024 + k0 + lk);
        }
        As[lk + 0][lr] = av.x; As[lk + 1][lr] = av.y; As[lk + 2][lr] = av.z; As[lk + 3][lr] = av.w;
        float4 wv = *reinterpret_cast<const float4*>(fh_w + (size_t)(bn + lr) * 1024 + k0 + lk);
        Ws[lk + 0][lr] = wv.x; Ws[lk + 1][lr] = wv.y; Ws[lk + 2][lr] = wv.z; Ws[lk + 3][lr] = wv.w;
        __syncthreads();
#pragma unroll
        for (int kk = 0; kk < 16; ++kk) {
            float4 a = *reinterpret_cast<const float4*>(&As[kk][ti << 2]);
            float4 b = *reinterpret_cast<const float4*>(&Ws[kk][tj << 2]);
            float ar[4] = {a.x, a.y, a.z, a.w};
            float br[4] = {b.x, b.y, b.z, b.w};
#pragma unroll
            for (int ii = 0; ii < 4; ++ii)
#pragma unroll
                for (int jj = 0; jj < 4; ++jj)
                    acc[ii][jj] = fmaf(ar[ii], br[jj], acc[ii][jj]);
        }
        __syncthreads();
    }
#pragma unroll
    for (int ii = 0; ii < 4; ++ii) {
        int r = bm + (ti << 2) + ii;
        if (r >= R) continue;
        int node = ph0 + (r >> 2);
        int cid = child_idx[node * KC + (r & 3)];
#pragma unroll
        for (int jj = 0; jj < 4; ++jj) {
            int j = bn + (tj << 2) + jj;
            float out = 0.f;
            if (cid >= 0) {
                float f = sigf(acc[ii][jj] + fh_b[j] + xf[(size_t)node * 1024 + j]);
                out = f * c_all[(size_t)cid * 1024 + j];
            }
            fcp[(size_t)r * 1024 + j] = out;
        }
    }
}

// ---------------------------------------------------------------------------
// Per-node relation matvec: chsum[nl,:] = Wrel[rel] @ hsum  (hsum = sum of child h)
// Identity relation (rel==48): chsum = hsum (skip 4MB read).
// grid (16 row-tiles of 64, M nodes), 256 thr = 4 waves; wave-per-row dot + shfl reduce.
// ---------------------------------------------------------------------------
__global__ __launch_bounds__(256)
void wmatvec(const float* __restrict__ h, const float* __restrict__ Wrel,
             const int* __restrict__ child_idx, const int* __restrict__ rel_ids,
             float* __restrict__ chsum, int ph0)
{
    __shared__ float hs[1024];
    const int nl = blockIdx.y;
    const int node = ph0 + nl;
    const int tid = threadIdx.x;
    const int c0 = child_idx[node * KC + 0], c1 = child_idx[node * KC + 1];
    const int c2 = child_idx[node * KC + 2], c3 = child_idx[node * KC + 3];
    for (int k = tid; k < 1024; k += 256) {
        float s = 0.f;
        if (c0 >= 0) s += h[(size_t)c0 * 1024 + k];
        if (c1 >= 0) s += h[(size_t)c1 * 1024 + k];
        if (c2 >= 0) s += h[(size_t)c2 * 1024 + k];
        if (c3 >= 0) s += h[(size_t)c3 * 1024 + k];
        hs[k] = s;
    }
    __syncthreads();
    const int rel = rel_ids[node];
    const int row0 = blockIdx.x * 64;
    if (rel == NREL) {  // identity
        if (tid < 64) chsum[(size_t)nl * 1024 + row0 + tid] = hs[row0 + tid];
        return;
    }
    const int wave = tid >> 6, lane = tid & 63;
    const float* Wb = Wrel + (size_t)rel * 1024 * 1024;
    for (int rr = wave; rr < 64; rr += 4) {
        const int row = row0 + rr;
        const float* wrow = Wb + (size_t)row * 1024;
        float acc = 0.f;
#pragma unroll
        for (int ii = 0; ii < 16; ++ii)
            acc = fmaf(wrow[lane + (ii << 6)], hs[lane + (ii << 6)], acc);
#pragma unroll
        for (int off = 32; off > 0; off >>= 1)
            acc += __shfl_down(acc, off);
        if (lane == 0) chsum[(size_t)nl * 1024 + row] = acc;
    }
}

// ---------------------------------------------------------------------------
// Leaves (nodes [0,384)): no children => iou = xi + iouh_b, fc = 0.
// ---------------------------------------------------------------------------
__global__ __launch_bounds__(256)
void leaf_kernel(const float* __restrict__ xi, const float* __restrict__ iouh_b,
                 float* __restrict__ c_all, float* __restrict__ hout)
{
    int idx = blockIdx.x * 256 + threadIdx.x;  // over 384*1024
    int n = idx >> 10, m = idx & 1023;
    const float* xr = xi + (size_t)n * 3072;
    float ig = sigf(xr[m] + iouh_b[m]);
    float og = sigf(xr[1024 + m] + iouh_b[1024 + m]);
    float ug = tanhf(xr[2048 + m] + iouh_b[2048 + m]);
    float c = ig * ug;
    c_all[idx] = c;
    hout[idx] = og * tanhf(c);
}

// ---------------------------------------------------------------------------
// Combine: c = sig(i)*tanh(u) + sum_c fcp; h = sig(o)*tanh(c)
// ---------------------------------------------------------------------------
__global__ __launch_bounds__(256)
void combine_kernel(const float* __restrict__ iou, const float* __restrict__ fcp,
                    float* __restrict__ c_all, float* __restrict__ hout,
                    int ph0, int M)
{
    int idx = blockIdx.x * 256 + threadIdx.x;
    if (idx >= M * 1024) return;
    int nl = idx >> 10, m = idx & 1023;
    int node = ph0 + nl;
    const float* ir = iou + (size_t)nl * 3072;
    float ig = sigf(ir[m]);
    float og = sigf(ir[1024 + m]);
    float ug = tanhf(ir[2048 + m]);
    float fc = fcp[(size_t)(nl * 4 + 0) * 1024 + m] + fcp[(size_t)(nl * 4 + 1) * 1024 + m]
             + fcp[(size_t)(nl * 4 + 2) * 1024 + m] + fcp[(size_t)(nl * 4 + 3) * 1024 + m];
    float c = ig * ug + fc;
    c_all[(size_t)node * 1024 + m] = c;
    hout[(size_t)node * 1024 + m] = og * tanhf(c);
}

extern "C" void kernel_launch(void* const* d_in, const int* in_sizes, int n_in,
                              void* d_out, int out_size, void* d_ws, size_t ws_size,
                              hipStream_t stream)
{
    const float* x       = (const float*)d_in[0];
    const float* Wrel    = (const float*)d_in[1];
    const float* ioux_w  = (const float*)d_in[2];
    const float* ioux_b  = (const float*)d_in[3];
    const float* iouh_w  = (const float*)d_in[4];
    const float* iouh_b  = (const float*)d_in[5];
    const float* fx_w    = (const float*)d_in[6];
    const float* fx_b    = (const float*)d_in[7];
    const float* fh_w    = (const float*)d_in[8];
    const float* fh_b    = (const float*)d_in[9];
    const int* child_idx = (const int*)d_in[10];
    const int* rel_ids   = (const int*)d_in[11];
    float* hout = (float*)d_out;

    // workspace layout (floats); total ~12 MB
    float* ws    = (float*)d_ws;
    float* xi    = ws;                       // 512*3072
    float* xf    = xi + 512 * 3072;          // 512*1024
    float* c_all = xf + 512 * 1024;          // 512*1024
    float* chsum = c_all + 512 * 1024;       // 64*1024
    float* iou   = chsum + 64 * 1024;        // 64*3072
    float* fcp   = iou + 64 * 3072;          // 256*1024

    // hoisted input projections
    gemm_xw<<<dim3(3072 / 64, 512 / 64), 256, 0, stream>>>(x, ioux_w, ioux_b, nullptr, xi, 512, 3072);
    gemm_xw<<<dim3(1024 / 64, 512 / 64), 256, 0, stream>>>(x, fx_w, fx_b, nullptr, xf, 512, 1024);

    // leaves
    leaf_kernel<<<dim3(384 * 1024 / 256), 256, 0, stream>>>(xi, iouh_b, c_all, hout);

    // internal phases (level-parallel, contiguous node ranges of the reversed 4-ary heap)
    const int ph0s[5] = {384, 427, 491, 507, 511};
    const int phM[5]  = {43, 64, 16, 4, 1};
    for (int p = 0; p < 5; ++p) {
        const int ph0 = ph0s[p], M = phM[p];
        wmatvec<<<dim3(16, M), 256, 0, stream>>>(hout, Wrel, child_idx, rel_ids, chsum, ph0);
        gemm_xw<<<dim3(3072 / 64, 1), 256, 0, stream>>>(chsum, iouh_w, iouh_b,
                                                        xi + (size_t)ph0 * 3072, iou, M, 3072);
        gemm_fgate<<<dim3(1024 / 64, (4 * M + 63) / 64), 256, 0, stream>>>(
            hout, c_all, fh_w, fh_b, xf, child_idx, fcp, ph0, M);
        combine_kernel<<<dim3((M * 1024 + 255) / 256), 256, 0, stream>>>(iou, fcp, c_all, hout, ph0, M);
    }
}

// Round 2
// 609.760 us; speedup vs baseline: 1.8865x; 1.8865x over previous
//
#include <hip/hip_runtime.h>
#include <hip/hip_bf16.h>
#include <stdint.h>

// ChildSumTreeLSTM, N=512, K=4, IN_DIM=MEM=1024, R=48 (+identity slot 48).
// Reversed 4-ary heap => level ranges: leaves [0,384); internal phases
// [384,427),[427,491),[491,507),[507,511),[511,512).
// This round: bf16 MFMA (16x16x32) for all GEMMs, fp32 state everywhere else.

#define KC 4
#define NREL 48

typedef __attribute__((ext_vector_type(8))) short s8v;     // 8 bf16 = 4 VGPR
typedef __attribute__((ext_vector_type(4))) float f32x4;

__device__ __forceinline__ float sigf(float x){ return 1.f/(1.f+__expf(-x)); }
__device__ __forceinline__ unsigned short f2bf(float x){
    union { float f; unsigned u; } v; v.f = x;
    unsigned r = v.u + 0x7fffu + ((v.u >> 16) & 1u);
    return (unsigned short)(r >> 16);
}

// ---------------------------------------------------------------------------
// Convert fp32 -> bf16, contiguous dst rows: x(512) | ioux_w(3072) | fx_w(1024)
// | iouh_w(3072) | fh_w(1024).  One block per 1024-elem row.
// ---------------------------------------------------------------------------
__global__ __launch_bounds__(256)
void conv_all(const float* __restrict__ x,  const float* __restrict__ w0,
              const float* __restrict__ w1, const float* __restrict__ w2,
              const float* __restrict__ w3, unsigned short* __restrict__ dst)
{
    int row = blockIdx.x, t = threadIdx.x;
    const float* src; int lr;
    if      (row < 512)  { src = x;  lr = row; }
    else if (row < 3584) { src = w0; lr = row - 512; }
    else if (row < 4608) { src = w1; lr = row - 3584; }
    else if (row < 7680) { src = w2; lr = row - 4608; }
    else                 { src = w3; lr = row - 7680; }
    float4 v = *reinterpret_cast<const float4*>(src + (size_t)lr * 1024 + t * 4);
    ushort4 o; o.x = f2bf(v.x); o.y = f2bf(v.y); o.z = f2bf(v.z); o.w = f2bf(v.w);
    *reinterpret_cast<ushort4*>(dst + (size_t)row * 1024 + t * 4) = o;
}

// ---------------------------------------------------------------------------
// bf16 MFMA GEMM: C[m,j] = sum_k A[m,k]*B[j,k] (+bias[j]) (+add[m,j])
// A,B row-major K=1024 contiguous (B^T form). 256 thr = 4 waves (2x2),
// wave tile (BM/2)x(BN/2), 16x16x32 MFMA, fp32 accum.
// EPI 0: store C=acc+bias(+add), f32.  EPI 1 (f-gate): A-rows gathered from
// hbf[child_idx] (zrow for pads); store sigmoid(acc+fh_b+xf[node])*c_all[cid].
// ---------------------------------------------------------------------------
template<int BM, int BN, int EPI>
__global__ __launch_bounds__(256)
void gemm_mfma(const unsigned short* __restrict__ A, const unsigned short* __restrict__ B,
               const float* __restrict__ bias, const float* __restrict__ add,
               float* __restrict__ C, int NC,
               const unsigned short* __restrict__ hbf, const unsigned short* __restrict__ zrow,
               const int* __restrict__ child_idx, const float* __restrict__ c_all,
               const float* __restrict__ xf, int ph0, int Rvalid)
{
    constexpr int FM = BM / 32, FN = BN / 32, AR = BM / 64, BR = BN / 64;
    __shared__ unsigned short As[BM * 32];
    __shared__ unsigned short Bs[BN * 32];
    const int tid = threadIdx.x;
    const int bm = blockIdx.y * BM, bn = blockIdx.x * BN;
    const int wave = tid >> 6, lane = tid & 63;
    const int wr = (wave >> 1) * (BM / 2), wc = (wave & 1) * (BN / 2);
    const int l15 = lane & 15, g = lane >> 4;
    const int srow = tid >> 2, skc = (tid & 3) * 8;

    const unsigned short* aptr[AR];
#pragma unroll
    for (int i = 0; i < AR; ++i) {
        int r = bm + i * 64 + srow;
        if constexpr (EPI == 1) {
            const unsigned short* p = zrow;
            if (r < Rvalid) {
                int cid = child_idx[(ph0 + (r >> 2)) * KC + (r & 3)];
                if (cid >= 0) p = hbf + (size_t)cid * 1024;
            }
            aptr[i] = p;
        } else {
            aptr[i] = A + (size_t)r * 1024;
        }
    }

    f32x4 acc[FM][FN];
#pragma unroll
    for (int m = 0; m < FM; ++m)
#pragma unroll
        for (int n = 0; n < FN; ++n) acc[m][n] = (f32x4){0.f, 0.f, 0.f, 0.f};

    for (int k0 = 0; k0 < 1024; k0 += 32) {
        if (k0) __syncthreads();
#pragma unroll
        for (int i = 0; i < AR; ++i) {
            s8v v = *reinterpret_cast<const s8v*>(aptr[i] + k0 + skc);
            *reinterpret_cast<s8v*>(&As[(i * 64 + srow) * 32 + skc]) = v;
        }
#pragma unroll
        for (int i = 0; i < BR; ++i) {
            s8v v = *reinterpret_cast<const s8v*>(B + (size_t)(bn + i * 64 + srow) * 1024 + k0 + skc);
            *reinterpret_cast<s8v*>(&Bs[(i * 64 + srow) * 32 + skc]) = v;
        }
        __syncthreads();
        s8v af[FM], bfv[FN];
#pragma unroll
        for (int m = 0; m < FM; ++m)
            af[m] = *reinterpret_cast<const s8v*>(&As[(wr + m * 16 + l15) * 32 + g * 8]);
#pragma unroll
        for (int n = 0; n < FN; ++n)
            bfv[n] = *reinterpret_cast<const s8v*>(&Bs[(wc + n * 16 + l15) * 32 + g * 8]);
#pragma unroll
        for (int m = 0; m < FM; ++m)
#pragma unroll
            for (int n = 0; n < FN; ++n)
                acc[m][n] = __builtin_amdgcn_mfma_f32_16x16x32_bf16(af[m], bfv[n], acc[m][n], 0, 0, 0);
    }

    // C/D layout (HW-verified): col = lane&15, row = 4*(lane>>4) + reg
#pragma unroll
    for (int m = 0; m < FM; ++m) {
#pragma unroll
        for (int n = 0; n < FN; ++n) {
#pragma unroll
            for (int q = 0; q < 4; ++q) {
                int row = bm + wr + m * 16 + g * 4 + q;
                int col = bn + wc + n * 16 + l15;
                float v = acc[m][n][q];
                if constexpr (EPI == 0) {
                    v += bias[col];
                    if (add) v += add[(size_t)row * NC + col];
                    C[(size_t)row * NC + col] = v;
                } else {
                    if (row < Rvalid) {
                        int node = ph0 + (row >> 2);
                        int cid = child_idx[node * KC + (row & 3)];
                        float out = 0.f;
                        if (cid >= 0) {
                            float f = sigf(v + bias[col] + xf[(size_t)node * 1024 + col]);
                            out = f * c_all[(size_t)cid * 1024 + col];
                        }
                        C[(size_t)row * 1024 + col] = out;
                    }
                }
            }
        }
    }
}

// ---------------------------------------------------------------------------
// Per-node relation matvec: chsum_bf[nl,:] = bf16( Wrel[rel] @ sum_children h )
// Identity relation (rel==48, root): pass-through. fp32, memory-bound.
// ---------------------------------------------------------------------------
__global__ __launch_bounds__(256)
void wmatvec(const float* __restrict__ h, const float* __restrict__ Wrel,
             const int* __restrict__ child_idx, const int* __restrict__ rel_ids,
             unsigned short* __restrict__ chsum_bf, int ph0)
{
    __shared__ float hs[1024];
    const int nl = blockIdx.y;
    const int node = ph0 + nl;
    const int tid = threadIdx.x;
    const int c0 = child_idx[node * KC + 0], c1 = child_idx[node * KC + 1];
    const int c2 = child_idx[node * KC + 2], c3 = child_idx[node * KC + 3];
    for (int k = tid; k < 1024; k += 256) {
        float s = 0.f;
        if (c0 >= 0) s += h[(size_t)c0 * 1024 + k];
        if (c1 >= 0) s += h[(size_t)c1 * 1024 + k];
        if (c2 >= 0) s += h[(size_t)c2 * 1024 + k];
        if (c3 >= 0) s += h[(size_t)c3 * 1024 + k];
        hs[k] = s;
    }
    __syncthreads();
    const int rel = rel_ids[node];
    const int row0 = blockIdx.x * 64;
    if (rel == NREL) {  // identity
        if (tid < 64) chsum_bf[(size_t)nl * 1024 + row0 + tid] = f2bf(hs[row0 + tid]);
        return;
    }
    const int wave = tid >> 6, lane = tid & 63;
    const float* Wb = Wrel + (size_t)rel * 1024 * 1024;
    for (int rr = wave; rr < 64; rr += 4) {
        const int row = row0 + rr;
        const float* wrow = Wb + (size_t)row * 1024;
        float acc = 0.f;
#pragma unroll
        for (int ii = 0; ii < 16; ++ii)
            acc = fmaf(wrow[lane + (ii << 6)], hs[lane + (ii << 6)], acc);
#pragma unroll
        for (int off = 32; off > 0; off >>= 1)
            acc += __shfl_down(acc, off);
        if (lane == 0) chsum_bf[(size_t)nl * 1024 + row] = f2bf(acc);
    }
}

// ---------------------------------------------------------------------------
// Leaves [0,384): iou = xi + iouh_b, fc = 0.
// ---------------------------------------------------------------------------
__global__ __launch_bounds__(256)
void leaf_kernel(const float* __restrict__ xi, const float* __restrict__ iouh_b,
                 float* __restrict__ c_all, float* __restrict__ hout,
                 unsigned short* __restrict__ hbf)
{
    int idx = blockIdx.x * 256 + threadIdx.x;  // over 384*1024
    int n = idx >> 10, m = idx & 1023;
    const float* xr = xi + (size_t)n * 3072;
    float ig = sigf(xr[m] + iouh_b[m]);
    float og = sigf(xr[1024 + m] + iouh_b[1024 + m]);
    float ug = tanhf(xr[2048 + m] + iouh_b[2048 + m]);
    float c = ig * ug;
    float hv = og * tanhf(c);
    c_all[idx] = c;
    hout[idx] = hv;
    hbf[idx] = f2bf(hv);
}

// ---------------------------------------------------------------------------
// Combine: c = sig(i)*tanh(u) + sum_children fcp; h = sig(o)*tanh(c)
// ---------------------------------------------------------------------------
__global__ __launch_bounds__(256)
void combine_kernel(const float* __restrict__ iou, const float* __restrict__ fcp,
                    float* __restrict__ c_all, float* __restrict__ hout,
                    unsigned short* __restrict__ hbf, int ph0, int M)
{
    int idx = blockIdx.x * 256 + threadIdx.x;
    if (idx >= M * 1024) return;
    int nl = idx >> 10, m = idx & 1023;
    int node = ph0 + nl;
    const float* ir = iou + (size_t)nl * 3072;
    float ig = sigf(ir[m]);
    float og = sigf(ir[1024 + m]);
    float ug = tanhf(ir[2048 + m]);
    float fc = fcp[(size_t)(nl * 4 + 0) * 1024 + m] + fcp[(size_t)(nl * 4 + 1) * 1024 + m]
             + fcp[(size_t)(nl * 4 + 2) * 1024 + m] + fcp[(size_t)(nl * 4 + 3) * 1024 + m];
    float c = ig * ug + fc;
    float hv = og * tanhf(c);
    c_all[(size_t)node * 1024 + m] = c;
    hout[(size_t)node * 1024 + m] = hv;
    hbf[(size_t)node * 1024 + m] = f2bf(hv);
}

extern "C" void kernel_launch(void* const* d_in, const int* in_sizes, int n_in,
                              void* d_out, int out_size, void* d_ws, size_t ws_size,
                              hipStream_t stream)
{
    const float* x       = (const float*)d_in[0];
    const float* Wrel    = (const float*)d_in[1];
    const float* ioux_w  = (const float*)d_in[2];
    const float* ioux_b  = (const float*)d_in[3];
    const float* iouh_w  = (const float*)d_in[4];
    const float* iouh_b  = (const float*)d_in[5];
    const float* fx_w    = (const float*)d_in[6];
    const float* fx_b    = (const float*)d_in[7];
    const float* fh_w    = (const float*)d_in[8];
    const float* fh_b    = (const float*)d_in[9];
    const int* child_idx = (const int*)d_in[10];
    const int* rel_ids   = (const int*)d_in[11];
    float* hout = (float*)d_out;

    // bf16 region (contiguous rows for conv_all): xb | ioux_wb | fx_wb | iouh_wb | fh_wb
    unsigned short* xb       = (unsigned short*)d_ws;
    unsigned short* ioux_wb  = xb + (size_t)512 * 1024;
    unsigned short* fx_wb    = ioux_wb + (size_t)3072 * 1024;
    unsigned short* iouh_wb  = fx_wb + (size_t)1024 * 1024;
    unsigned short* fh_wb    = iouh_wb + (size_t)3072 * 1024;
    unsigned short* hbf      = fh_wb + (size_t)1024 * 1024;
    unsigned short* chsum_bf = hbf + (size_t)512 * 1024;     // 64 rows (padded)
    unsigned short* zrow     = chsum_bf + (size_t)64 * 1024; // 1024 bf16 (poison ok: tiny denormals, outputs forced 0)
    // f32 region at 19 MB
    float* xi    = (float*)((char*)d_ws + (size_t)19 * 1024 * 1024); // 512*3072
    float* xf    = xi + (size_t)512 * 3072;                          // 512*1024
    float* c_all = xf + (size_t)512 * 1024;                          // 512*1024
    float* iou   = c_all + (size_t)512 * 1024;                       // 64*3072
    float* fcp   = iou + (size_t)64 * 3072;                          // 256*1024

    // 1) fp32 -> bf16 conversions (one kernel, 8704 rows)
    conv_all<<<8704, 256, 0, stream>>>(x, ioux_w, fx_w, iouh_w, fh_w, xb);

    // 2) hoisted input projections (bf16 MFMA, fp32 out)
    gemm_mfma<128, 128, 0><<<dim3(24, 4), 256, 0, stream>>>(
        xb, ioux_wb, ioux_b, nullptr, xi, 3072,
        nullptr, nullptr, nullptr, nullptr, nullptr, 0, 0);
    gemm_mfma<128, 128, 0><<<dim3(8, 4), 256, 0, stream>>>(
        xb, fx_wb, fx_b, nullptr, xf, 1024,
        nullptr, nullptr, nullptr, nullptr, nullptr, 0, 0);

    // 3) leaves
    leaf_kernel<<<1536, 256, 0, stream>>>(xi, iouh_b, c_all, hout, hbf);

    // 4) internal phases
    const int ph0s[5] = {384, 427, 491, 507, 511};
    const int phM[5]  = {43, 64, 16, 4, 1};
    for (int p = 0; p < 5; ++p) {
        const int ph0 = ph0s[p], M = phM[p];
        wmatvec<<<dim3(16, M), 256, 0, stream>>>(hout, Wrel, child_idx, rel_ids, chsum_bf, ph0);
        // iou = chsum @ iouh_w^T + iouh_b + xi[ph0..]; rows padded to 64 (garbage rows unused)
        gemm_mfma<64, 64, 0><<<dim3(48, 1), 256, 0, stream>>>(
            chsum_bf, iouh_wb, iouh_b, xi + (size_t)ph0 * 3072, iou, 3072,
            nullptr, nullptr, nullptr, nullptr, nullptr, 0, 0);
        // fcp[r,:] = sigmoid(hbf[cid] @ fh_w^T + fh_b + xf[node]) * c_all[cid]
        gemm_mfma<64, 64, 1><<<dim3(16, (4 * M + 63) / 64), 256, 0, stream>>>(
            nullptr, fh_wb, fh_b, nullptr, fcp, 1024,
            hbf, zrow, child_idx, c_all, xf, ph0, 4 * M);
        combine_kernel<<<dim3((M * 1024 + 255) / 256), 256, 0, stream>>>(
            iou, fcp, c_all, hout, hbf, ph0, M);
    }
}

// Round 3
// 470.358 us; speedup vs baseline: 2.4456x; 1.2964x over previous
//
#include <hip/hip_runtime.h>
#include <hip/hip_bf16.h>

// ChildSumTreeLSTM, N=512, K=4, IN_DIM=MEM=1024, R=48 (+identity slot 48).
// Reversed 4-ary heap => level ranges: leaves [0,384); internal phases
// [384,427),[427,491),[491,507),[507,511),[511,512).
// Round 3: split-K(x4) double-buffered bf16 MFMA phase GEMMs, LDS stride 40
// (bank-conflict fix), wmatvec+fgate merged per phase, xi/xf merged with
// on-the-fly fp32->bf16 conversion. 18 dispatches.

#define KC 4
#define NREL 48
#define LDSW 40   // LDS row stride in shorts (80 B) — breaks 8-way bank conflict

typedef __attribute__((ext_vector_type(8))) short s8v;     // 8 bf16 = 4 VGPR
typedef __attribute__((ext_vector_type(4))) float f32x4;

__device__ __forceinline__ float sigf(float x){ return 1.f/(1.f+__expf(-x)); }
__device__ __forceinline__ unsigned short f2bf(float x){
    union { float f; unsigned u; } v; v.f = x;
    unsigned r = v.u + 0x7fffu + ((v.u >> 16) & 1u);
    return (unsigned short)(r >> 16);
}

// ---------------------------------------------------------------------------
// prep: fp32->bf16 for iouh_w (3072x1024) || fh_w (1024x1024) into contiguous dst
// ---------------------------------------------------------------------------
__global__ __launch_bounds__(256)
void prep_conv(const float* __restrict__ iouh_w, const float* __restrict__ fh_w,
               unsigned short* __restrict__ dst)
{
    size_t i = (size_t)blockIdx.x * 256 + threadIdx.x;   // 1,048,576 float4 units
    const float* src = (i < 786432) ? (iouh_w + i * 4) : (fh_w + (i - 786432) * 4);
    float4 v = *reinterpret_cast<const float4*>(src);
    ushort4 o; o.x = f2bf(v.x); o.y = f2bf(v.y); o.z = f2bf(v.z); o.w = f2bf(v.w);
    *reinterpret_cast<ushort4*>(dst + i * 4) = o;
}

// ---------------------------------------------------------------------------
// xproj: xi = x @ ioux_w^T + ioux_b (cols 0..3071) and xf = x @ fx_w^T + fx_b.
// Reads fp32 A/B, converts to bf16 during staging. 128x128 tile, reg-prefetch
// double buffer, grid (32,4): bx<24 -> ioux tile, else fx tile.
// ---------------------------------------------------------------------------
__global__ __launch_bounds__(256)
void xproj(const float* __restrict__ x, const float* __restrict__ ioux_w,
           const float* __restrict__ fx_w, const float* __restrict__ ioux_b,
           const float* __restrict__ fx_b, float* __restrict__ xi, float* __restrict__ xf)
{
    __shared__ unsigned short As[128 * LDSW];
    __shared__ unsigned short Bs[128 * LDSW];
    const int tid = threadIdx.x;
    const bool isfx = blockIdx.x >= 24;
    const float* W    = isfx ? fx_w : ioux_w;
    const float* bias = isfx ? fx_b : ioux_b;
    float* C          = isfx ? xf : xi;
    const int NC      = isfx ? 1024 : 3072;
    const int bn = (isfx ? (blockIdx.x - 24) : (int)blockIdx.x) * 128;
    const int bm = blockIdx.y * 128;
    const int wave = tid >> 6, lane = tid & 63;
    const int wr = (wave >> 1) * 64, wc = (wave & 1) * 64;
    const int l15 = lane & 15, g = lane >> 4;
    const int srow = tid >> 1, sk = (tid & 1) * 16;      // 128 rows x 32 k

    const float* Ap = x + (size_t)(bm + srow) * 1024 + sk;
    const float* Bp = W + (size_t)(bn + srow) * 1024 + sk;

    f32x4 acc[4][4];
#pragma unroll
    for (int m = 0; m < 4; ++m)
#pragma unroll
        for (int n = 0; n < 4; ++n) acc[m][n] = (f32x4){0.f, 0.f, 0.f, 0.f};

    float4 a0, a1, a2, a3, b0, b1, b2, b3;
#define LOADT(K0) do { const float* _a = Ap + (K0); const float* _b = Bp + (K0); \
    a0 = *(const float4*)_a; a1 = *(const float4*)(_a + 4); \
    a2 = *(const float4*)(_a + 8); a3 = *(const float4*)(_a + 12); \
    b0 = *(const float4*)_b; b1 = *(const float4*)(_b + 4); \
    b2 = *(const float4*)(_b + 8); b3 = *(const float4*)(_b + 12); } while (0)

    LOADT(0);
    for (int k0 = 0; k0 < 1024; k0 += 32) {
        if (k0) __syncthreads();
        unsigned short* as = &As[srow * LDSW + sk];
        unsigned short* bs = &Bs[srow * LDSW + sk];
        s8v v;
        v[0]=(short)f2bf(a0.x); v[1]=(short)f2bf(a0.y); v[2]=(short)f2bf(a0.z); v[3]=(short)f2bf(a0.w);
        v[4]=(short)f2bf(a1.x); v[5]=(short)f2bf(a1.y); v[6]=(short)f2bf(a1.z); v[7]=(short)f2bf(a1.w);
        *(s8v*)as = v;
        v[0]=(short)f2bf(a2.x); v[1]=(short)f2bf(a2.y); v[2]=(short)f2bf(a2.z); v[3]=(short)f2bf(a2.w);
        v[4]=(short)f2bf(a3.x); v[5]=(short)f2bf(a3.y); v[6]=(short)f2bf(a3.z); v[7]=(short)f2bf(a3.w);
        *(s8v*)(as + 8) = v;
        v[0]=(short)f2bf(b0.x); v[1]=(short)f2bf(b0.y); v[2]=(short)f2bf(b0.z); v[3]=(short)f2bf(b0.w);
        v[4]=(short)f2bf(b1.x); v[5]=(short)f2bf(b1.y); v[6]=(short)f2bf(b1.z); v[7]=(short)f2bf(b1.w);
        *(s8v*)bs = v;
        v[0]=(short)f2bf(b2.x); v[1]=(short)f2bf(b2.y); v[2]=(short)f2bf(b2.z); v[3]=(short)f2bf(b2.w);
        v[4]=(short)f2bf(b3.x); v[5]=(short)f2bf(b3.y); v[6]=(short)f2bf(b3.z); v[7]=(short)f2bf(b3.w);
        *(s8v*)(bs + 8) = v;
        __syncthreads();
        if (k0 < 992) LOADT(k0 + 32);
        s8v af[4], bfv[4];
#pragma unroll
        for (int m = 0; m < 4; ++m)
            af[m] = *(const s8v*)&As[(wr + m * 16 + l15) * LDSW + g * 8];
#pragma unroll
        for (int n = 0; n < 4; ++n)
            bfv[n] = *(const s8v*)&Bs[(wc + n * 16 + l15) * LDSW + g * 8];
#pragma unroll
        for (int m = 0; m < 4; ++m)
#pragma unroll
            for (int n = 0; n < 4; ++n)
                acc[m][n] = __builtin_amdgcn_mfma_f32_16x16x32_bf16(af[m], bfv[n], acc[m][n], 0, 0, 0);
    }
#undef LOADT
    // C/D layout: col = lane&15, row = 4*(lane>>4) + reg
#pragma unroll
    for (int m = 0; m < 4; ++m)
#pragma unroll
        for (int n = 0; n < 4; ++n)
#pragma unroll
            for (int q = 0; q < 4; ++q) {
                int row = bm + wr + m * 16 + g * 4 + q;
                int col = bn + wc + n * 16 + l15;
                C[(size_t)row * NC + col] = acc[m][n][q] + bias[col];
            }
}

// ---------------------------------------------------------------------------
// Leaves [0,384): iou = xi + iouh_b, fc = 0.
// ---------------------------------------------------------------------------
__global__ __launch_bounds__(256)
void leaf_kernel(const float* __restrict__ xi, const float* __restrict__ iouh_b,
                 float* __restrict__ c_all, float* __restrict__ hout,
                 unsigned short* __restrict__ hbf)
{
    int idx = blockIdx.x * 256 + threadIdx.x;  // over 384*1024
    int n = idx >> 10, m = idx & 1023;
    const float* xr = xi + (size_t)n * 3072;
    float ig = sigf(xr[m] + iouh_b[m]);
    float og = sigf(xr[1024 + m] + iouh_b[1024 + m]);
    float ug = tanhf(xr[2048 + m] + iouh_b[2048 + m]);
    float c = ig * ug;
    float hv = og * tanhf(c);
    c_all[idx] = c;
    hout[idx] = hv;
    hbf[idx] = f2bf(hv);
}

// ---------------------------------------------------------------------------
// k1: merged {wmatvec (16*M blocks)} U {fgate split-K partial GEMM}.
// wmatvec: chsum_bf[nl,:] = bf16(Wrel[rel] @ sum_children h); identity for root.
// fgate:   fraw[kc][r][c] = sum_{k in kc*256..+256} hbf[cid(r)][k]*fh_wb[c][k]
//          (rows gathered via child_idx; sigmoid deferred to combine)
// ---------------------------------------------------------------------------
__global__ __launch_bounds__(256)
void k1_phase(const float* __restrict__ h, const float* __restrict__ Wrel,
              const int* __restrict__ child_idx, const int* __restrict__ rel_ids,
              unsigned short* __restrict__ chsum_bf,
              const unsigned short* __restrict__ hbf, const unsigned short* __restrict__ fh_wb,
              float* __restrict__ fraw, int ph0, int M)
{
    __shared__ float hs[1024];
    __shared__ unsigned short As[64 * LDSW];
    __shared__ unsigned short Bs[64 * LDSW];
    const int tid = threadIdx.x;
    const int wm_blocks = 16 * M;
    const int wave = tid >> 6, lane = tid & 63;

    if ((int)blockIdx.x < wm_blocks) {
        // ---------------- wmatvec ----------------
        const int nl = blockIdx.x >> 4;
        const int rowt = blockIdx.x & 15;
        const int node = ph0 + nl;
        const int c0 = child_idx[node * KC + 0], c1 = child_idx[node * KC + 1];
        const int c2 = child_idx[node * KC + 2], c3 = child_idx[node * KC + 3];
        for (int k = tid; k < 1024; k += 256) {
            float s = 0.f;
            if (c0 >= 0) s += h[(size_t)c0 * 1024 + k];
            if (c1 >= 0) s += h[(size_t)c1 * 1024 + k];
            if (c2 >= 0) s += h[(size_t)c2 * 1024 + k];
            if (c3 >= 0) s += h[(size_t)c3 * 1024 + k];
            hs[k] = s;
        }
        __syncthreads();
        const int rel = rel_ids[node];
        const int row0 = rowt * 64;
        if (rel == NREL) {  // identity (root)
            if (tid < 64) chsum_bf[(size_t)nl * 1024 + row0 + tid] = f2bf(hs[row0 + tid]);
            return;
        }
        const float* Wb = Wrel + (size_t)rel * 1024 * 1024;
        for (int rr = wave; rr < 32; rr += 4) {      // 2-row ILP: rr and rr+32
            const float* wa = Wb + (size_t)(row0 + rr) * 1024;
            const float* wb = Wb + (size_t)(row0 + rr + 32) * 1024;
            float aA = 0.f, aB = 0.f;
#pragma unroll
            for (int ii = 0; ii < 16; ++ii) {
                float hv = hs[lane + (ii << 6)];
                aA = fmaf(wa[lane + (ii << 6)], hv, aA);
                aB = fmaf(wb[lane + (ii << 6)], hv, aB);
            }
#pragma unroll
            for (int off = 32; off > 0; off >>= 1) {
                aA += __shfl_down(aA, off);
                aB += __shfl_down(aB, off);
            }
            if (lane == 0) {
                chsum_bf[(size_t)nl * 1024 + row0 + rr]      = f2bf(aA);
                chsum_bf[(size_t)nl * 1024 + row0 + rr + 32] = f2bf(aB);
            }
        }
        return;
    }
    // ---------------- fgate split-K partial ----------------
    const int idx = blockIdx.x - wm_blocks;
    const int kc = idx & 3;
    const int ct = (idx >> 2) & 15;
    const int rt = idx >> 6;
    const int r0 = rt * 64, cc0 = ct * 64, kbase = kc * 256;
    const int Rv = 4 * M;
    const int wr = (wave >> 1) * 32, wc = (wave & 1) * 32;
    const int l15 = lane & 15, g = lane >> 4;
    const int srow = tid >> 2, skc = (tid & 3) * 8;

    int r = r0 + srow;
    const unsigned short* ap = hbf;   // fallback row 0 (masked in combine)
    if (r < Rv) {
        int cid = child_idx[(ph0 + (r >> 2)) * KC + (r & 3)];
        if (cid >= 0) ap = hbf + (size_t)cid * 1024;
    }
    const unsigned short* bp = fh_wb + (size_t)(cc0 + srow) * 1024;

    f32x4 acc[2][2];
#pragma unroll
    for (int m = 0; m < 2; ++m)
#pragma unroll
        for (int n = 0; n < 2; ++n) acc[m][n] = (f32x4){0.f, 0.f, 0.f, 0.f};

    s8v ra = *(const s8v*)(ap + kbase + skc);
    s8v rb = *(const s8v*)(bp + kbase + skc);
    for (int ks = 0; ks < 8; ++ks) {
        if (ks) __syncthreads();
        *(s8v*)&As[srow * LDSW + skc] = ra;
        *(s8v*)&Bs[srow * LDSW + skc] = rb;
        __syncthreads();
        if (ks < 7) {
            ra = *(const s8v*)(ap + kbase + (ks + 1) * 32 + skc);
            rb = *(const s8v*)(bp + kbase + (ks + 1) * 32 + skc);
        }
        s8v af[2], bfv[2];
#pragma unroll
        for (int m = 0; m < 2; ++m)
            af[m] = *(const s8v*)&As[(wr + m * 16 + l15) * LDSW + g * 8];
#pragma unroll
        for (int n = 0; n < 2; ++n)
            bfv[n] = *(const s8v*)&Bs[(wc + n * 16 + l15) * LDSW + g * 8];
#pragma unroll
        for (int m = 0; m < 2; ++m)
#pragma unroll
            for (int n = 0; n < 2; ++n)
                acc[m][n] = __builtin_amdgcn_mfma_f32_16x16x32_bf16(af[m], bfv[n], acc[m][n], 0, 0, 0);
    }
#pragma unroll
    for (int m = 0; m < 2; ++m)
#pragma unroll
        for (int n = 0; n < 2; ++n)
#pragma unroll
            for (int q = 0; q < 4; ++q) {
                int row = r0 + wr + m * 16 + g * 4 + q;
                int col = cc0 + wc + n * 16 + l15;
                if (row < Rv) fraw[(size_t)(kc * 256 + row) * 1024 + col] = acc[m][n][q];
            }
}

// ---------------------------------------------------------------------------
// k2: iou split-K partial: ioup[kc][row][col] = sum_{k in kc-chunk} chsum_bf[row][k]*iouh_wb[col][k]
// grid (48, 4). Rows padded to 64 (garbage rows unused by combine).
// ---------------------------------------------------------------------------
__global__ __launch_bounds__(256)
void k2_iou(const unsigned short* __restrict__ chsum_bf, const unsigned short* __restrict__ iouh_wb,
            float* __restrict__ ioup)
{
    __shared__ unsigned short As[64 * LDSW];
    __shared__ unsigned short Bs[64 * LDSW];
    const int tid = threadIdx.x;
    const int cc0 = blockIdx.x * 64;
    const int kc = blockIdx.y, kbase = kc * 256;
    const int wave = tid >> 6, lane = tid & 63;
    const int wr = (wave >> 1) * 32, wc = (wave & 1) * 32;
    const int l15 = lane & 15, g = lane >> 4;
    const int srow = tid >> 2, skc = (tid & 3) * 8;

    const unsigned short* ap = chsum_bf + (size_t)srow * 1024;
    const unsigned short* bp = iouh_wb + (size_t)(cc0 + srow) * 1024;

    f32x4 acc[2][2];
#pragma unroll
    for (int m = 0; m < 2; ++m)
#pragma unroll
        for (int n = 0; n < 2; ++n) acc[m][n] = (f32x4){0.f, 0.f, 0.f, 0.f};

    s8v ra = *(const s8v*)(ap + kbase + skc);
    s8v rb = *(const s8v*)(bp + kbase + skc);
    for (int ks = 0; ks < 8; ++ks) {
        if (ks) __syncthreads();
        *(s8v*)&As[srow * LDSW + skc] = ra;
        *(s8v*)&Bs[srow * LDSW + skc] = rb;
        __syncthreads();
        if (ks < 7) {
            ra = *(const s8v*)(ap + kbase + (ks + 1) * 32 + skc);
            rb = *(const s8v*)(bp + kbase + (ks + 1) * 32 + skc);
        }
        s8v af[2], bfv[2];
#pragma unroll
        for (int m = 0; m < 2; ++m)
            af[m] = *(const s8v*)&As[(wr + m * 16 + l15) * LDSW + g * 8];
#pragma unroll
        for (int n = 0; n < 2; ++n)
            bfv[n] = *(const s8v*)&Bs[(wc + n * 16 + l15) * LDSW + g * 8];
#pragma unroll
        for (int m = 0; m < 2; ++m)
#pragma unroll
            for (int n = 0; n < 2; ++n)
                acc[m][n] = __builtin_amdgcn_mfma_f32_16x16x32_bf16(af[m], bfv[n], acc[m][n], 0, 0, 0);
    }
#pragma unroll
    for (int m = 0; m < 2; ++m)
#pragma unroll
        for (int n = 0; n < 2; ++n)
#pragma unroll
            for (int q = 0; q < 4; ++q) {
                int row = wr + m * 16 + g * 4 + q;
                int col = cc0 + wc + n * 16 + l15;
                ioup[(size_t)(kc * 64 + row) * 3072 + col] = acc[m][n][q];
            }
}

// ---------------------------------------------------------------------------
// combine: sum split-K partials, gates, c/h update.
// ---------------------------------------------------------------------------
__global__ __launch_bounds__(256)
void combine_kernel(const float* __restrict__ ioup, const float* __restrict__ fraw,
                    const float* __restrict__ xi, const float* __restrict__ xf,
                    const float* __restrict__ iouh_b, const float* __restrict__ fh_b,
                    const int* __restrict__ child_idx, float* __restrict__ c_all,
                    float* __restrict__ hout, unsigned short* __restrict__ hbf,
                    int ph0, int M)
{
    int idx = blockIdx.x * 256 + threadIdx.x;
    if (idx >= M * 1024) return;
    int nl = idx >> 10, m = idx & 1023;
    int node = ph0 + nl;
    float iv = iouh_b[m]        + xi[(size_t)node * 3072 + m];
    float ov = iouh_b[1024 + m] + xi[(size_t)node * 3072 + 1024 + m];
    float uv = iouh_b[2048 + m] + xi[(size_t)node * 3072 + 2048 + m];
#pragma unroll
    for (int kc = 0; kc < 4; ++kc) {
        const float* p = ioup + (size_t)(kc * 64 + nl) * 3072;
        iv += p[m]; ov += p[1024 + m]; uv += p[2048 + m];
    }
    float ig = sigf(iv), og = sigf(ov), ug = tanhf(uv);
    float fc = 0.f;
    float xfv = xf[(size_t)node * 1024 + m] + fh_b[m];
#pragma unroll
    for (int c = 0; c < KC; ++c) {
        int cid = child_idx[node * KC + c];
        if (cid >= 0) {
            float raw = xfv;
#pragma unroll
            for (int kc = 0; kc < 4; ++kc)
                raw += fraw[(size_t)(kc * 256 + nl * 4 + c) * 1024 + m];
            fc += sigf(raw) * c_all[(size_t)cid * 1024 + m];
        }
    }
    float cv = ig * ug + fc;
    float hv = og * tanhf(cv);
    c_all[(size_t)node * 1024 + m] = cv;
    hout[(size_t)node * 1024 + m] = hv;
    hbf[(size_t)node * 1024 + m] = f2bf(hv);
}

extern "C" void kernel_launch(void* const* d_in, const int* in_sizes, int n_in,
                              void* d_out, int out_size, void* d_ws, size_t ws_size,
                              hipStream_t stream)
{
    const float* x       = (const float*)d_in[0];
    const float* Wrel    = (const float*)d_in[1];
    const float* ioux_w  = (const float*)d_in[2];
    const float* ioux_b  = (const float*)d_in[3];
    const float* iouh_w  = (const float*)d_in[4];
    const float* iouh_b  = (const float*)d_in[5];
    const float* fx_w    = (const float*)d_in[6];
    const float* fx_b    = (const float*)d_in[7];
    const float* fh_w    = (const float*)d_in[8];
    const float* fh_b    = (const float*)d_in[9];
    const int* child_idx = (const int*)d_in[10];
    const int* rel_ids   = (const int*)d_in[11];
    float* hout = (float*)d_out;

    char* w = (char*)d_ws;
    unsigned short* iouh_wb  = (unsigned short*)(w);                         // 6 MB
    unsigned short* fh_wb    = (unsigned short*)(w + 6u * 1024 * 1024);      // 2 MB (contiguous after iouh_wb)
    unsigned short* hbf      = (unsigned short*)(w + 8u * 1024 * 1024);      // 1 MB
    unsigned short* chsum_bf = (unsigned short*)(w + 9u * 1024 * 1024);      // 128 KB (64 rows)
    float* xi    = (float*)(w + 10u * 1024 * 1024);                          // 6 MB
    float* xf    = (float*)(w + 16u * 1024 * 1024);                          // 2 MB
    float* c_all = (float*)(w + 18u * 1024 * 1024);                          // 2 MB
    float* ioup  = (float*)(w + 20u * 1024 * 1024);                          // 3 MB  [4][64][3072]
    float* fraw  = (float*)(w + 23u * 1024 * 1024);                          // 4 MB  [4][256][1024]

    // 1) convert iouh_w/fh_w to bf16 (ioux_w/fx_w converted on the fly in xproj)
    prep_conv<<<4096, 256, 0, stream>>>(iouh_w, fh_w, iouh_wb);

    // 2) xi and xf in one launch
    xproj<<<dim3(32, 4), 256, 0, stream>>>(x, ioux_w, fx_w, ioux_b, fx_b, xi, xf);

    // 3) leaves
    leaf_kernel<<<1536, 256, 0, stream>>>(xi, iouh_b, c_all, hout, hbf);

    // 4) internal phases: {wmatvec ∪ fgate} -> iou -> combine
    const int ph0s[5] = {384, 427, 491, 507, 511};
    const int phM[5]  = {43, 64, 16, 4, 1};
    for (int p = 0; p < 5; ++p) {
        const int ph0 = ph0s[p], M = phM[p];
        const int rt = (4 * M + 63) / 64;
        k1_phase<<<16 * M + 64 * rt, 256, 0, stream>>>(
            hout, Wrel, child_idx, rel_ids, chsum_bf, hbf, fh_wb, fraw, ph0, M);
        k2_iou<<<dim3(48, 4), 256, 0, stream>>>(chsum_bf, iouh_wb, ioup);
        combine_kernel<<<4 * M, 256, 0, stream>>>(
            ioup, fraw, xi, xf, iouh_b, fh_b, child_idx, c_all, hout, hbf, ph0, M);
    }
}